// Round 2
// baseline (562.512 us; speedup 1.0000x reference)
//
#include <hip/hip_runtime.h>

// Fused gated aggregator:
//   gates = sigmoid(nodes @ Wg + bg); data = nodes @ Wt + bt
//   out[B,D] = owner_masks(float) @ (data * gates)
// v2: masks bit-packed into LDS once per block (ballot), main loop streams
// nodes only (sequential); per-wave vt_s removes one barrier (2/chunk).

#define NTOT   500000
#define NBLK   500
#define NCHUNK 15625   // NTOT / 32, exact

typedef unsigned long long u64;
typedef unsigned int u32;

typedef __attribute__((ext_vector_type(8))) unsigned short ushort8;
typedef __bf16 bf16x8 __attribute__((ext_vector_type(8)));
typedef __attribute__((ext_vector_type(4))) float f32x4;

static __device__ __forceinline__ unsigned short f2bf(float f) {
  u32 u = __float_as_uint(f);
  u += 0x7fffu + ((u >> 16) & 1u);  // RNE
  return (unsigned short)(u >> 16);
}

static __device__ __forceinline__ u64 pack4(unsigned short a, unsigned short b,
                                            unsigned short c, unsigned short d) {
  return (u64)a | ((u64)b << 16) | ((u64)c << 32) | ((u64)d << 48);
}

// 2-bit -> packed bf16 pair {0.0 or 1.0, 0.0 or 1.0}
static __device__ __forceinline__ u32 bits2bf2(u32 byte, int j) {
  return ((byte >> j) & 1u ? 0x3F80u : 0u) | ((byte >> (j + 1)) & 1u ? 0x3F800000u : 0u);
}

template <bool ATOMIC>
__global__ __launch_bounds__(256, 2)
void agg_main(const float* __restrict__ nodes, const int* __restrict__ masks,
              const float* __restrict__ Wt, const float* __restrict__ bt,
              const float* __restrict__ Wg, const float* __restrict__ bg,
              float* __restrict__ outp) {
  // stride 136 shorts: 68 dwords == 4 mod 32 -> 2-way max on frag reads (free)
  __shared__ __align__(16) unsigned short nodes_s[32][136];  // 8.5 KB
  // mask bits: row-stride 17 ull (136 B == 34 dwords == 2 mod 32 -> 2-way)
  __shared__ __align__(16) u64 bits[128][17];                // 17 KB
  // stride 40 shorts: 80 B, 16B-aligned rows; 20 dwords stride -> 2-way max
  __shared__ __align__(16) unsigned short vt_s[128][40];     // 10 KB

  const int tid = threadIdx.x;
  const int lane = tid & 63;
  const int w = tid >> 6;    // wave 0..3
  const int q = lane >> 4;   // quad 0..3
  const int r = lane & 15;

  const int bid = blockIdx.x;
  const int c0 = (int)(((long long)bid * NCHUNK) / NBLK);
  const int c1 = (int)(((long long)(bid + 1) * NCHUNK) / NBLK);
  const int nch = c1 - c0;   // 31 or 32 chunks
  const int n0 = c0 * 32;    // block's first node; n0+1023 < NTOT for all blocks

  // ---- preload W as B-operand fragments (VGPR-resident), + biases ----
  // B-frag for 16x16x32: n = lane&15, k = quad*8 + j. Wave w owns d in [32w,32w+32).
  bf16x8 Wf[2][4][2];  // [data/gate][ks][nt]
  float btr[2], bgr[2];
#pragma unroll
  for (int nt = 0; nt < 2; ++nt) {
    const int d = w * 32 + nt * 16 + r;
    btr[nt] = bt[d];
    bgr[nt] = bg[d];
#pragma unroll
    for (int ks = 0; ks < 4; ++ks) {
      ushort8 ft, fg;
#pragma unroll
      for (int j = 0; j < 8; ++j) {
        const int k = ks * 32 + q * 8 + j;
        ft[j] = f2bf(Wt[k * 128 + d]);
        fg[j] = f2bf(Wg[k * 128 + d]);
      }
      Wf[0][ks][nt] = __builtin_bit_cast(bf16x8, ft);
      Wf[1][ks][nt] = __builtin_bit_cast(bf16x8, fg);
    }
  }

  // ---- stage mask bits: wave w packs rows [32w, 32w+32), 1024 cols ----
  {
    const int row0 = w * 32;
    int cur[32], nxt[32];
#pragma unroll
    for (int k = 0; k < 32; ++k)
      cur[k] = masks[(size_t)(row0 + k) * NTOT + n0 + lane];
#pragma unroll
    for (int g = 0; g < 16; ++g) {
      if (g < 15) {
#pragma unroll
        for (int k = 0; k < 32; ++k)
          nxt[k] = masks[(size_t)(row0 + k) * NTOT + n0 + (g + 1) * 64 + lane];
      }
      u64 v = 0;
#pragma unroll
      for (int k = 0; k < 32; ++k) {
        u64 bl = __ballot(cur[k] != 0);
        if (lane == k) v = bl;
      }
      if (lane < 32) bits[row0 + lane][g] = v;
      if (g < 15) {
#pragma unroll
        for (int k = 0; k < 32; ++k) cur[k] = nxt[k];
      }
    }
  }

  // pooling accumulators: wave w owns out[128 b][32 d] -> 8 mt x 2 nt tiles
  f32x4 acc[8][2];
  const f32x4 fzero = {0.f, 0.f, 0.f, 0.f};
#pragma unroll
  for (int i = 0; i < 8; ++i) {
    acc[i][0] = fzero;
    acc[i][1] = fzero;
  }

  float4 nf[4];
  auto issue = [&](int cloc) {
    const int k0 = n0 + cloc * 32;
#pragma unroll
    for (int it = 0; it < 4; ++it) {
      const int flat = it * 256 + tid;            // 0..1023 over 32 rows x 32 f4
      const int nrow = flat >> 5, nc4 = flat & 31;
      nf[it] = *(const float4*)(nodes + (size_t)(k0 + nrow) * 128 + nc4 * 4);
    }
  };

  issue(0);
  __syncthreads();  // bits visible to all waves; doubles as first barrier A

  const u32* bitw = (const u32*)bits;  // dword view: row*34 + cloc

  for (int c = 0; c < nch; ++c) {
    if (c) __syncthreads();  // barrier A: prev chunk's nodes_s reads done
    // ---- regs -> LDS (fp32 -> bf16) ----
#pragma unroll
    for (int it = 0; it < 4; ++it) {
      const int flat = it * 256 + tid;
      const int nrow = flat >> 5, nc4 = flat & 31;
      *(u64*)&nodes_s[nrow][nc4 * 4] =
          pack4(f2bf(nf[it].x), f2bf(nf[it].y), f2bf(nf[it].z), f2bf(nf[it].w));
    }
    __syncthreads();  // barrier B
    if (c + 1 < nch) issue(c + 1);  // prefetch next chunk under compute

    // ---- GEMM1: [32 nodes x 128 s] @ W -> V cols for this wave's 32 d ----
    f32x4 aD[2][2], aG[2][2];
#pragma unroll
    for (int i = 0; i < 2; ++i)
#pragma unroll
      for (int j = 0; j < 2; ++j) { aD[i][j] = fzero; aG[i][j] = fzero; }
#pragma unroll
    for (int ks = 0; ks < 4; ++ks) {
      bf16x8 a0 = *(const bf16x8*)&nodes_s[r][ks * 32 + q * 8];
      bf16x8 a1 = *(const bf16x8*)&nodes_s[16 + r][ks * 32 + q * 8];
#pragma unroll
      for (int nt = 0; nt < 2; ++nt) {
        aD[0][nt] = __builtin_amdgcn_mfma_f32_16x16x32_bf16(a0, Wf[0][ks][nt], aD[0][nt], 0, 0, 0);
        aD[1][nt] = __builtin_amdgcn_mfma_f32_16x16x32_bf16(a1, Wf[0][ks][nt], aD[1][nt], 0, 0, 0);
        aG[0][nt] = __builtin_amdgcn_mfma_f32_16x16x32_bf16(a0, Wf[1][ks][nt], aG[0][nt], 0, 0, 0);
        aG[1][nt] = __builtin_amdgcn_mfma_f32_16x16x32_bf16(a1, Wf[1][ks][nt], aG[1][nt], 0, 0, 0);
      }
    }

    // ---- epilogue: V = (data+bt)*sigmoid(gate+bg) -> vt_s[d][node] ----
    // C/D layout: col(d) = lane&15, row(node) = quad*4 + reg (+16*mt)
    // vt_s rows [32w, 32w+32) are private to this wave -> no barrier needed.
#pragma unroll
    for (int mt = 0; mt < 2; ++mt)
#pragma unroll
      for (int nt = 0; nt < 2; ++nt) {
        const int d = w * 32 + nt * 16 + r;
        unsigned short t[4];
#pragma unroll
        for (int reg = 0; reg < 4; ++reg) {
          const float x = aD[mt][nt][reg] + btr[nt];
          const float g = aG[mt][nt][reg] + bgr[nt];
          t[reg] = f2bf(x / (1.f + __expf(-g)));
        }
        *(u64*)&vt_s[d][mt * 16 + q * 4] = pack4(t[0], t[1], t[2], t[3]);
      }

    // ---- pooling: out[b][d] += mask_bit * V[node][d], K = 32 nodes ----
    bf16x8 bfr[2];
#pragma unroll
    for (int nt = 0; nt < 2; ++nt)
      bfr[nt] = *(const bf16x8*)&vt_s[w * 32 + nt * 16 + r][q * 8];
#pragma unroll
    for (int mt = 0; mt < 8; ++mt) {
      // A-frag from bits: row b = mt*16+r, cols c*32 + q*8 + (0..7)
      const u32 dw = bitw[(mt * 16 + r) * 34 + c];
      const u32 byte = (dw >> (q * 8)) & 0xffu;
      u32 p0 = bits2bf2(byte, 0), p1 = bits2bf2(byte, 2);
      u32 p2 = bits2bf2(byte, 4), p3 = bits2bf2(byte, 6);
      u32 af[4] = {p0, p1, p2, p3};
      bf16x8 a = __builtin_bit_cast(bf16x8, *(ushort8*)af);
#pragma unroll
      for (int nt = 0; nt < 2; ++nt)
        acc[mt][nt] = __builtin_amdgcn_mfma_f32_16x16x32_bf16(a, bfr[nt], acc[mt][nt], 0, 0, 0);
    }
  }

  // ---- write per-block partial (or atomic accumulate) ----
#pragma unroll
  for (int mt = 0; mt < 8; ++mt)
#pragma unroll
    for (int nt = 0; nt < 2; ++nt)
#pragma unroll
      for (int reg = 0; reg < 4; ++reg) {
        const int b = mt * 16 + q * 4 + reg;
        const int d = w * 32 + nt * 16 + r;
        if (ATOMIC)
          atomicAdd(&outp[b * 128 + d], acc[mt][nt][reg]);
        else
          outp[(size_t)bid * 16384 + b * 128 + d] = acc[mt][nt][reg];
      }
}

__global__ __launch_bounds__(256)
void agg_reduce(const float* __restrict__ part, float* __restrict__ out) {
  // 256 blocks x 256 thr = 65536 = 16384 outputs x 4 groups; 125 partials each
  const int gid = blockIdx.x * 256 + threadIdx.x;
  const int i = gid & 16383;
  const int grp = gid >> 14;  // 0..3
  const float* p = part + (size_t)grp * 125 * 16384 + i;
  float s = 0.f;
#pragma unroll 5
  for (int g = 0; g < 125; ++g) s += p[(size_t)g * 16384];
  atomicAdd(&out[i], s);
}

extern "C" void kernel_launch(void* const* d_in, const int* in_sizes, int n_in,
                              void* d_out, int out_size, void* d_ws, size_t ws_size,
                              hipStream_t stream) {
  const float* nodes = (const float*)d_in[0];
  const int*   masks = (const int*)d_in[1];
  const float* Wt    = (const float*)d_in[2];
  const float* bt    = (const float*)d_in[3];
  const float* Wg    = (const float*)d_in[4];
  const float* bg    = (const float*)d_in[5];
  float* out = (float*)d_out;

  hipMemsetAsync(d_out, 0, (size_t)out_size * sizeof(float), stream);

  const size_t need = (size_t)NBLK * 16384 * sizeof(float);
  if (ws_size >= need) {
    agg_main<false><<<NBLK, 256, 0, stream>>>(nodes, masks, Wt, bt, Wg, bg, (float*)d_ws);
    agg_reduce<<<256, 256, 0, stream>>>((const float*)d_ws, out);
  } else {
    agg_main<true><<<NBLK, 256, 0, stream>>>(nodes, masks, Wt, bt, Wg, bg, out);
  }
}

// Round 4
// 535.629 us; speedup vs baseline: 1.0502x; 1.0502x over previous
//
#include <hip/hip_runtime.h>

// Fused gated aggregator:
//   gates = sigmoid(nodes @ Wg + bg); data = nodes @ Wt + bt
//   out[B,D] = owner_masks(float) @ (data * gates)
// v3b: 512-thread blocks, wave owns 16 d-cols (Wf 32 + acc 32 regs) so
// __launch_bounds__(512,4) gives 16 waves/CU (2x v2 occupancy). Mask
// prologue packs bits via int4 loads + VALU (no ballot). f2bf2 hand-rolled
// RNE (bit_cast of __hip_bfloat162 doesn't compile).

#define NTOT   500000
#define NBLK   512
#define NCHUNK 15625   // NTOT / 32, exact

typedef unsigned long long u64;
typedef unsigned int u32;

typedef __attribute__((ext_vector_type(8))) unsigned short ushort8;
typedef __bf16 bf16x8 __attribute__((ext_vector_type(8)));
typedef __attribute__((ext_vector_type(4))) float f32x4;

static __device__ __forceinline__ u32 f2bf1(float f) {
  u32 u = __float_as_uint(f);
  u += 0x7fffu + ((u >> 16) & 1u);  // RNE
  return u >> 16;
}

static __device__ __forceinline__ u32 f2bf2(float a, float b) {
  return f2bf1(a) | (f2bf1(b) << 16);
}

// 2 bits -> packed pair of bf16 {0,1}
static __device__ __forceinline__ u32 bits2bf2(u32 byte, int j) {
  return ((byte >> j) & 1u ? 0x3F80u : 0u) | ((byte >> (j + 1)) & 1u ? 0x3F800000u : 0u);
}

template <bool ATOMIC>
__global__ __launch_bounds__(512, 4)
void agg_main(const float* __restrict__ nodes, const int* __restrict__ masks,
              const float* __restrict__ Wt, const float* __restrict__ bt,
              const float* __restrict__ Wg, const float* __restrict__ bg,
              float* __restrict__ outp) {
  __shared__ __align__(16) unsigned short nodes_s[32][136];  // 8.5 KB
  __shared__ __align__(16) u64 bits[128][17];                // 17 KB (34-dword rows)
  __shared__ __align__(16) unsigned short vt_s[128][40];     // 10 KB

  const int tid = threadIdx.x;
  const int lane = tid & 63;
  const int w = tid >> 6;    // wave 0..7
  const int q = lane >> 4;   // quad 0..3
  const int r = lane & 15;

  const int bid = blockIdx.x;
  const int c0 = (int)(((long long)bid * NCHUNK) >> 9);
  const int c1 = (int)(((long long)(bid + 1) * NCHUNK) >> 9);
  const int nch = c1 - c0;   // 30 or 31
  const int n0 = c0 * 32;

  // ---- prologue: pack mask bits. wave w packs rows [16w, 16w+16). ----
  // lane l covers cols [16l, 16l+16) of this block's window (<=992 used).
  {
    const int row0 = w * 16;
    int cb = 16 * lane;
    if (cb >= nch * 32) cb = 0;  // clamp: those u16s are never read
    int4 cur[4], nxt[4];
    auto ldrow = [&](int rr, int4* dst) {
      const int* p = masks + (size_t)(row0 + rr) * NTOT + n0 + cb;
#pragma unroll
      for (int i = 0; i < 4; ++i) dst[i] = *(const int4*)(p + 4 * i);
    };
    ldrow(0, cur);
#pragma unroll 4
    for (int rr = 0; rr < 16; ++rr) {
      if (rr < 15) ldrow(rr + 1, nxt);
      const int* m = (const int*)cur;
      u32 b = 0;
#pragma unroll
      for (int e = 0; e < 16; ++e) b |= (u32)(m[e] != 0) << e;
      ((unsigned short*)bits)[(row0 + rr) * 68 + lane] = (unsigned short)b;
#pragma unroll
      for (int i = 0; i < 4; ++i) cur[i] = nxt[i];
    }
  }

  // ---- W as B-operand fragments; wave w owns d in [16w, 16w+16) ----
  // B-frag 16x16x32: n = lane&15, k = quad*8 + j
  bf16x8 Wf[2][4];  // [data/gate][ks] -> 32 VGPRs
  float btr, bgr;
  {
    const int d = w * 16 + r;
    btr = bt[d];
    bgr = bg[d];
#pragma unroll
    for (int ks = 0; ks < 4; ++ks) {
      u32 wv[4], gv[4];
#pragma unroll
      for (int j = 0; j < 4; ++j) {
        const int k = ks * 32 + q * 8 + 2 * j;
        wv[j] = f2bf2(Wt[k * 128 + d], Wt[(k + 1) * 128 + d]);
        gv[j] = f2bf2(Wg[k * 128 + d], Wg[(k + 1) * 128 + d]);
      }
      Wf[0][ks] = __builtin_bit_cast(bf16x8, *(ushort8*)wv);
      Wf[1][ks] = __builtin_bit_cast(bf16x8, *(ushort8*)gv);
    }
  }

  // pooling accumulators: wave w owns out[128 b][16 d] -> 8 mt tiles
  const f32x4 fzero = {0.f, 0.f, 0.f, 0.f};
  f32x4 acc[8];
#pragma unroll
  for (int i = 0; i < 8; ++i) acc[i] = fzero;

  float4 nf[2];
  auto issue = [&](int cloc) {
    const int k0 = n0 + cloc * 32;
#pragma unroll
    for (int it = 0; it < 2; ++it) {
      const int flat = it * 512 + tid;  // 0..1023 over 32 rows x 32 float4
      const int nrow = flat >> 5, nc4 = flat & 31;
      nf[it] = *(const float4*)(nodes + (size_t)(k0 + nrow) * 128 + nc4 * 4);
    }
  };

  issue(0);
  __syncthreads();  // bits visible to all waves

  const u32* bitw = (const u32*)bits;  // row stride 34 dwords

  for (int c = 0; c < nch; ++c) {
    if (c) __syncthreads();  // barrier A: prev chunk's nodes_s reads done
#pragma unroll
    for (int it = 0; it < 2; ++it) {
      const int flat = it * 512 + tid;
      const int nrow = flat >> 5, nc4 = flat & 31;
      const u32 lo = f2bf2(nf[it].x, nf[it].y);
      const u32 hi = f2bf2(nf[it].z, nf[it].w);
      *(u64*)&nodes_s[nrow][nc4 * 4] = (u64)lo | ((u64)hi << 32);
    }
    __syncthreads();  // barrier B
    if (c + 1 < nch) issue(c + 1);  // prefetch under compute

    // ---- GEMM1: [32 nodes x 128 s] @ W -> this wave's 16 d-cols ----
    f32x4 aD[2], aG[2];
    aD[0] = fzero; aD[1] = fzero; aG[0] = fzero; aG[1] = fzero;
#pragma unroll
    for (int ks = 0; ks < 4; ++ks) {
      bf16x8 a0 = *(const bf16x8*)&nodes_s[r][ks * 32 + q * 8];
      bf16x8 a1 = *(const bf16x8*)&nodes_s[16 + r][ks * 32 + q * 8];
      aD[0] = __builtin_amdgcn_mfma_f32_16x16x32_bf16(a0, Wf[0][ks], aD[0], 0, 0, 0);
      aD[1] = __builtin_amdgcn_mfma_f32_16x16x32_bf16(a1, Wf[0][ks], aD[1], 0, 0, 0);
      aG[0] = __builtin_amdgcn_mfma_f32_16x16x32_bf16(a0, Wf[1][ks], aG[0], 0, 0, 0);
      aG[1] = __builtin_amdgcn_mfma_f32_16x16x32_bf16(a1, Wf[1][ks], aG[1], 0, 0, 0);
    }

    // ---- epilogue: V = (data+bt)*sigmoid(gate+bg) -> vt_s[d][node] ----
    // C/D layout: col(d) = lane&15, row(node) = quad*4 + reg (+16*mt).
    // vt_s rows [16w,16w+16) are wave-private: no barrier needed.
    const int d = w * 16 + r;
#pragma unroll
    for (int mt = 0; mt < 2; ++mt) {
      float v[4];
#pragma unroll
      for (int reg = 0; reg < 4; ++reg) {
        const float x = aD[mt][reg] + btr;
        const float g = aG[mt][reg] + bgr;
        v[reg] = x * __builtin_amdgcn_rcpf(1.f + __expf(-g));
      }
      const u32 lo = f2bf2(v[0], v[1]);
      const u32 hi = f2bf2(v[2], v[3]);
      *(u64*)&vt_s[d][mt * 16 + q * 4] = (u64)lo | ((u64)hi << 32);
    }

    // ---- pooling: out[b][d] += mask_bit * V[node][d], K = 32 ----
    // B-frag: n(d) = lane&15 -> row d of vt_s; k(node) = quad*8 + j
    bf16x8 bfr = *(const bf16x8*)&vt_s[d][q * 8];
#pragma unroll
    for (int mt = 0; mt < 8; ++mt) {
      const u32 dw = bitw[(mt * 16 + r) * 34 + c];
      const u32 byte = (dw >> (q * 8)) & 0xffu;
      u32 p[4];
      p[0] = bits2bf2(byte, 0);
      p[1] = bits2bf2(byte, 2);
      p[2] = bits2bf2(byte, 4);
      p[3] = bits2bf2(byte, 6);
      bf16x8 a = __builtin_bit_cast(bf16x8, *(ushort8*)p);
      acc[mt] = __builtin_amdgcn_mfma_f32_16x16x32_bf16(a, bfr, acc[mt], 0, 0, 0);
    }
  }

  // ---- write per-block partial (or atomic accumulate) ----
#pragma unroll
  for (int mt = 0; mt < 8; ++mt)
#pragma unroll
    for (int reg = 0; reg < 4; ++reg) {
      const int b = mt * 16 + q * 4 + reg;
      const int d = w * 16 + r;
      if (ATOMIC)
        atomicAdd(&outp[b * 128 + d], acc[mt][reg]);
      else
        outp[(size_t)bid * 16384 + b * 128 + d] = acc[mt][reg];
    }
}

__global__ __launch_bounds__(256)
void agg_reduce(const float* __restrict__ part, float* __restrict__ out) {
  // 512 blocks x 256 thr = 131072 = 8 groups x 16384 outputs; 64 partials each
  const int gid = blockIdx.x * 256 + threadIdx.x;
  const int i = gid & 16383;
  const int grp = gid >> 14;
  const float* p = part + (size_t)grp * 64 * 16384 + i;
  float s = 0.f;
#pragma unroll 8
  for (int g = 0; g < 64; ++g) s += p[(size_t)g * 16384];
  atomicAdd(&out[i], s);
}

extern "C" void kernel_launch(void* const* d_in, const int* in_sizes, int n_in,
                              void* d_out, int out_size, void* d_ws, size_t ws_size,
                              hipStream_t stream) {
  const float* nodes = (const float*)d_in[0];
  const int*   masks = (const int*)d_in[1];
  const float* Wt    = (const float*)d_in[2];
  const float* bt    = (const float*)d_in[3];
  const float* Wg    = (const float*)d_in[4];
  const float* bg    = (const float*)d_in[5];
  float* out = (float*)d_out;

  (void)hipMemsetAsync(d_out, 0, (size_t)out_size * sizeof(float), stream);

  const size_t need = (size_t)NBLK * 16384 * sizeof(float);
  if (ws_size >= need) {
    agg_main<false><<<NBLK, 512, 0, stream>>>(nodes, masks, Wt, bt, Wg, bg, (float*)d_ws);
    agg_reduce<<<512, 256, 0, stream>>>((const float*)d_ws, out);
  } else {
    agg_main<true><<<NBLK, 512, 0, stream>>>(nodes, masks, Wt, bt, Wg, bg, out);
  }
}